// Round 13
// baseline (101.100 us; speedup 1.0000x reference)
//
#include <hip/hip_runtime.h>
#include <math.h>

typedef unsigned short u16;
typedef unsigned int u32;
typedef __bf16 bf16x8 __attribute__((ext_vector_type(8)));
typedef float f32x4 __attribute__((ext_vector_type(4)));

__device__ __forceinline__ u16 f2b(float f) {
  u32 u = __builtin_bit_cast(u32, f);
  u32 r = (u + 0x7FFFu + ((u >> 16) & 1u)) >> 16;
  return (u16)r;
}

__device__ __forceinline__ void glds16(const void* g, void* lds) {
  __builtin_amdgcn_global_load_lds(
      (const __attribute__((address_space(1))) void*)(void*)(const_cast<void*>(g)),
      (__attribute__((address_space(3))) void*)lds, 16, 0, 0);
}

// scale folded with log2(e) so softmax uses native exp2 (v_exp_f32); validated R11/R12
#define QSCALE (0.08838834764831845f * 1.4426950408889634f)

// ---------------- merged prep kernel (castx | buildw | wpe) ----------------
__global__ __launch_bounds__(256) void prep_all(
    const float* __restrict__ x, const float* __restrict__ Wq, const float* __restrict__ Wk,
    const float* __restrict__ Wv, const float* __restrict__ Wo,
    const float* __restrict__ pew, const float* __restrict__ peh,
    u16* __restrict__ xb, u16* __restrict__ WbigT, u16* __restrict__ WoT)
{
  __shared__ float wrow[512];
  const int bid = blockIdx.x;
  const int t = threadIdx.x;
  if (bid < 4096) {
    // castx
    int idx = bid * 256 + t;
    float4 v = ((const float4*)x)[idx];
    ushort4 o;
    o.x = f2b(v.x); o.y = f2b(v.y); o.z = f2b(v.z); o.w = f2b(v.w);
    ((ushort4*)xb)[idx] = o;
  } else if (bid < 6152) {
    // buildw
    int row = bid - 4096;  // 0..2055
    if (row < 512) {
      for (int k = t; k < 512; k += 256) WbigT[row*512 + k] = f2b(Wq[k*512 + row] * QSCALE);
    } else if (row < 1024) {
      int n = row - 512;
      for (int k = t; k < 512; k += 256) WbigT[row*512 + k] = f2b(Wk[k*512 + n]);
    } else if (row < 1536) {
      int n = row - 1024;
      for (int k = t; k < 512; k += 256) WbigT[row*512 + k] = f2b(Wv[k*512 + n]);
    } else if (row < 1544) {
      int rr = row - 1536 + 2040;
      for (int k = t; k < 512; k += 256) WbigT[rr*512 + k] = 0;
    } else {
      int n = row - 1544;
      for (int k = t; k < 512; k += 256) WoT[n*512 + k] = f2b(Wo[k*512 + n]);
    }
  } else {
    // wpe
    int k = bid - 6152;  // 0..511
    for (int j = t; j < 512; j += 256) wrow[j] = Wq[k*512 + j];
    __syncthreads();
    if (t < 252) {
      int h = t / 63, r = t - h*63;
      float aw = 0.f, ah = 0.f;
      for (int d = 0; d < 128; d++) {
        float qv = wrow[h*128 + d];
        aw += qv * pew[d*63 + r];
        ah += qv * peh[d*63 + r];
      }
      WbigT[(size_t)(1536 + t)*512 + k] = f2b(aw * QSCALE);
      WbigT[(size_t)(1788 + t)*512 + k] = f2b(ah * QSCALE);
    }
  }
}

// ---------------- fused QKV+REL GEMM: 256x256 tile, 8 waves, phase-interleaved (R10/R12) ------
__global__ __launch_bounds__(512) void gemm256(
    const u16* __restrict__ A, const u16* __restrict__ Bt,
    u16* __restrict__ Qb, u16* __restrict__ Kb, u16* __restrict__ Vt,
    float* __restrict__ RELW, float* __restrict__ RELH)
{
  __shared__ char sm[131072];
  const int tid = threadIdx.x;
  const int w = tid >> 6, l = tid & 63, g = l >> 4, c = l & 15;
  const int bm = blockIdx.x, bn = blockIdx.y;
  const int wm = w >> 2, wn = w & 3;

  f32x4 acc[8][4];
#pragma unroll
  for (int i = 0; i < 8; i++)
#pragma unroll
    for (int j = 0; j < 4; j++) acc[i][j] = f32x4{0.f, 0.f, 0.f, 0.f};

  const char* Ab = (const char*)A;
  const char* Bb = (const char*)Bt;
  const int rsub = l >> 3;
  const int csw = (((l & 7) ^ rsub) << 4);

#define A_STAGE(kb, p)                                                                    \
  {                                                                                       \
    char* As_ = sm + (p)*65536;                                                           \
    const int kbyte = (kb) * 128;                                                         \
    _Pragma("unroll")                                                                     \
    for (int i2 = 0; i2 < 4; i2++) {                                                      \
      const int row = i2*64 + w*8 + rsub;                                                 \
      glds16(Ab + (size_t)(bm*256 + row) * 1024 + kbyte + csw, As_ + i2*8192 + w*1024);   \
    }                                                                                     \
  }
#define B_STAGE(kb, p)                                                                    \
  {                                                                                       \
    char* Bs_ = sm + (p)*65536 + 32768;                                                   \
    const int kbyte = (kb) * 128;                                                         \
    _Pragma("unroll")                                                                     \
    for (int i2 = 0; i2 < 4; i2++) {                                                      \
      const int row = i2*64 + w*8 + rsub;                                                 \
      glds16(Bb + (size_t)(bn*256 + row) * 1024 + kbyte + csw, Bs_ + i2*8192 + w*1024);   \
    }                                                                                     \
  }

  B_STAGE(0, 0); A_STAGE(0, 0);
  B_STAGE(1, 1); A_STAGE(1, 1);

#pragma unroll
  for (int kb = 0; kb < 8; kb++) {
    const int p = kb & 1;
    if (kb == 0)      { asm volatile("s_waitcnt vmcnt(8)" ::: "memory"); }
    else if (kb < 7)  { asm volatile("s_waitcnt vmcnt(4)" ::: "memory"); }
    else              { asm volatile("s_waitcnt vmcnt(0)" ::: "memory"); }
    __builtin_amdgcn_s_barrier();

    const char* As_ = sm + p*65536;
    const char* Bs_ = As_ + 32768;

    bf16x8 bf[4][2], af[4][2];
#pragma unroll
    for (int ks = 0; ks < 2; ks++) {
      const int koff = (ks*64 + g*16) ^ ((c & 7) << 4);
#pragma unroll
      for (int mf = 0; mf < 4; mf++)
        af[mf][ks] = *(const bf16x8*)(As_ + (wm*128 + mf*16 + c)*128 + koff);
#pragma unroll
      for (int nf = 0; nf < 4; nf++)
        bf[nf][ks] = *(const bf16x8*)(Bs_ + (wn*64 + nf*16 + c)*128 + koff);
    }
    if (kb >= 1 && kb < 7) A_STAGE(kb + 1, p ^ 1);
    __builtin_amdgcn_s_setprio(1);
#pragma unroll
    for (int ks = 0; ks < 2; ks++)
#pragma unroll
      for (int mf = 0; mf < 4; mf++)
#pragma unroll
        for (int nf = 0; nf < 4; nf++)
          acc[mf][nf] = __builtin_amdgcn_mfma_f32_16x16x32_bf16(af[mf][ks], bf[nf][ks], acc[mf][nf], 0, 0, 0);
    __builtin_amdgcn_s_setprio(0);
    __builtin_amdgcn_s_barrier();

#pragma unroll
    for (int ks = 0; ks < 2; ks++) {
      const int koff = (ks*64 + g*16) ^ ((c & 7) << 4);
#pragma unroll
      for (int mf = 0; mf < 4; mf++)
        af[mf][ks] = *(const bf16x8*)(As_ + (wm*128 + (mf + 4)*16 + c)*128 + koff);
    }
    if (kb < 6) B_STAGE(kb + 2, p);
    __builtin_amdgcn_s_setprio(1);
#pragma unroll
    for (int ks = 0; ks < 2; ks++)
#pragma unroll
      for (int mf = 0; mf < 4; mf++)
#pragma unroll
        for (int nf = 0; nf < 4; nf++)
          acc[mf + 4][nf] = __builtin_amdgcn_mfma_f32_16x16x32_bf16(af[mf][ks], bf[nf][ks], acc[mf + 4][nf], 0, 0, 0);
    __builtin_amdgcn_s_setprio(0);
    __builtin_amdgcn_s_barrier();
  }
#undef A_STAGE
#undef B_STAGE

  const int b = bm >> 2;
  const int iBase = (bm & 3) * 256;

  if (bn < 4) {
    u16* dst0 = (bn < 2) ? Qb : Kb;
    const int bnn = bn & 1;
#pragma unroll
    for (int mf = 0; mf < 8; mf++) {
      const int lmb = wm*128 + mf*16 + g*4;
#pragma unroll
      for (int nf = 0; nf < 4; nf++) {
        const int ln = wn*64 + nf*16 + c;
#pragma unroll
        for (int r = 0; r < 4; r++) {
          const int lm = lmb + r;
          *(u16*)(sm + lm*512 + ((ln*2) ^ ((lm & 7) << 4))) = f2b(acc[mf][nf][r]);
        }
      }
    }
    __builtin_amdgcn_s_barrier();
#pragma unroll
    for (int it = 0; it < 16; it++) {
      const int gid = it*512 + tid;
      const int lm2 = gid >> 5, gsub = gid & 31;
      bf16x8 v = *(const bf16x8*)(sm + lm2*512 + ((gsub*16) ^ ((lm2 & 7) << 4)));
      const int h = bnn*2 + (gsub >> 4);
      const int d0 = (gsub & 15) * 8;
      *(bf16x8*)(dst0 + ((size_t)(b*4 + h)*1024 + iBase + lm2)*128 + d0) = v;
    }
  } else if (bn < 6) {
#pragma unroll
    for (int mf = 0; mf < 8; mf++) {
      const int lmb = wm*128 + mf*16 + g*4;
#pragma unroll
      for (int nf = 0; nf < 4; nf++) {
        const int ln = wn*64 + nf*16 + c;
        u32 w0, w1;
        asm("v_cvt_pk_bf16_f32 %0, %1, %2" : "=v"(w0) : "v"(acc[mf][nf][0]), "v"(acc[mf][nf][1]));
        asm("v_cvt_pk_bf16_f32 %0, %1, %2" : "=v"(w1) : "v"(acc[mf][nf][2]), "v"(acc[mf][nf][3]));
        uint2 pk; pk.x = w0; pk.y = w1;
        *(uint2*)(sm + ln*512 + ((lmb*2) ^ ((c & 7) << 4))) = pk;
      }
    }
    __builtin_amdgcn_s_barrier();
#pragma unroll
    for (int it = 0; it < 16; it++) {
      const int gid = it*512 + tid;
      const int ln2 = gid >> 5, gsub = gid & 31;
      bf16x8 v = *(const bf16x8*)(sm + ln2*512 + ((gsub*16) ^ ((ln2 & 7) << 4)));
      const int q2 = (bn - 4)*256 + ln2;
      const int h = q2 >> 7, d = q2 & 127;
      *(bf16x8*)(Vt + ((size_t)(b*4 + h)*128 + d)*1024 + iBase + gsub*8) = v;
    }
  } else {
#pragma unroll
    for (int mf = 0; mf < 8; mf++) {
      const int lmb = wm*128 + mf*16 + g*4;
#pragma unroll
      for (int nf = 0; nf < 4; nf++) {
        const int q = (bn - 6)*256 + wn*64 + nf*16 + c;
        if (q < 252) {
          const int h = q / 63, r2 = q - h*63;
#pragma unroll
          for (int r = 0; r < 4; r++)
            RELW[(size_t)((b*4 + h)*1024 + iBase + lmb + r)*64 + r2] = acc[mf][nf][r];
        } else if (q < 504) {
          const int qq = q - 252;
          const int h = qq / 63, r2 = qq - h*63;
#pragma unroll
          for (int r = 0; r < 4; r++)
            RELH[(size_t)((b*4 + h)*1024 + iBase + lmb + r)*64 + r2] = acc[mf][nf][r];
        }
      }
    }
  }
}

// ---------------- fused flash attention, T15 QK-ahead pipeline ----------------
// LDS: Kbuf0 @0, Kbuf1 @16K, Vbuf0 @32K, Vbuf1 @48K, Pl @64K (8KB) = 72KB.
// Per iter jt: [wait vmcnt; bar] K_STAGE(jt+2) ; QK(jt+1)->acc2[(jt+1)&1] ;
//              SM(jt) on acc2[jt&1] ; PV(jt) ; [bar] V_STAGE(jt+2).
// QK(jt+1) has no dependence on SM(jt) -> its MFMA/ds_read stream executes under
// softmax's serial VALU chain. K(jt+2) legal post-entry-bar (K(jt) last read in
// iter jt-1); V(jt+2) legal post-end-bar (V(jt) read in PV(jt)).
__global__ __launch_bounds__(256) void attn_fused(
    const u16* __restrict__ Qb, const u16* __restrict__ Kb, const u16* __restrict__ Vt,
    const float* __restrict__ RELW, const float* __restrict__ RELH,
    u16* __restrict__ AO)
{
  __shared__ char sm[73728];
  char* const Pl = sm + 65536;
  const int tid = threadIdx.x;
  const int w = tid >> 6, l = tid & 63, g = l >> 4, c = l & 15;
  const int bh = blockIdx.x, qt = blockIdx.y;
  const int i0 = qt * 64;

  bf16x8 qf[4];
  {
    const char* qbase = (const char*)Qb + (size_t)(bh*1024 + i0 + w*16 + c) * 256;
#pragma unroll
    for (int s = 0; s < 4; s++) qf[s] = *(const bf16x8*)(qbase + s*64 + g*16);
  }

  const int i = i0 + w*16 + c;
  const int xi = i & 31, yi = i >> 5;
  const float* rw = RELW + ((size_t)(bh*1024 + i) << 6);
  const float* rhb = RELH + ((size_t)(bh*1024 + i) << 6) + (31 - yi);
  float xwh[2][4];
#pragma unroll
  for (int e = 0; e < 2; e++)
#pragma unroll
    for (int r = 0; r < 4; r++) xwh[e][r] = rw[e*16 + g*4 + r - xi + 31];

#define K_STAGE(jt, p)                                                                     \
  {                                                                                        \
    char* Kt_ = sm + (p)*16384;                                                            \
    const int j0b = (jt) * 64;                                                             \
    _Pragma("unroll")                                                                      \
    for (int t = 0; t < 4; t++) {                                                          \
      const int L = (w*4 + t)*1024 + l*16;                                                 \
      const int jr = L >> 8, jb = L & 255;                                                 \
      glds16((const char*)Kb + (size_t)(bh*1024 + j0b + jr) * 256 + (jb ^ ((jr & 7) << 4)),\
             Kt_ + L);                                                                     \
    }                                                                                      \
  }
#define V_STAGE(jt, p)                                                                     \
  {                                                                                        \
    char* Vs_ = sm + 32768 + (p)*16384;                                                    \
    const int j0b = (jt) * 64;                                                             \
    _Pragma("unroll")                                                                      \
    for (int t = 0; t < 4; t++) {                                                          \
      const int L = (w*4 + t)*1024 + l*16;                                                 \
      const int dr = L >> 7, db = L & 127;                                                 \
      glds16((const char*)Vt + (size_t)(bh*128 + dr) * 2048 + j0b*2 + (db ^ ((dr & 7) << 4)),\
             Vs_ + L);                                                                     \
    }                                                                                      \
  }
  // QK of tile jtX from Kbuf (jtX&1) into accX (zero-init inside)
#define QK_COMPUTE(jtX, accX)                                                              \
  {                                                                                        \
    const char* Kt_ = sm + ((jtX) & 1)*16384;                                              \
    _Pragma("unroll")                                                                      \
    for (int fn = 0; fn < 4; fn++) (accX)[fn] = f32x4{0.f, 0.f, 0.f, 0.f};                 \
    __builtin_amdgcn_s_setprio(1);                                                         \
    _Pragma("unroll")                                                                      \
    for (int s = 0; s < 4; s++) {                                                          \
      const int koff = (s*64 + g*16) ^ ((c & 7) << 4);                                     \
      _Pragma("unroll")                                                                    \
      for (int fn = 0; fn < 4; fn++) {                                                     \
        bf16x8 kf = *(const bf16x8*)(Kt_ + (fn*16 + c)*256 + koff);                        \
        (accX)[fn] = __builtin_amdgcn_mfma_f32_16x16x32_bf16(kf, qf[s], (accX)[fn], 0, 0, 0);\
      }                                                                                    \
    }                                                                                      \
    __builtin_amdgcn_s_setprio(0);                                                         \
  }

  f32x4 Oacc[8];
#pragma unroll
  for (int fd = 0; fd < 8; fd++) Oacc[fd] = f32x4{0.f, 0.f, 0.f, 0.f};
  float m_q = -INFINITY, l_q = 0.f;
  f32x4 acc2[2][4];

  // prologue: yh first (oldest vmem), then K0,K1,V0,V1 (16 ops)
  float yh0 = rhb[0], yh1 = rhb[1];
  asm volatile("" ::: "memory");
  K_STAGE(0, 0);
  K_STAGE(1, 1);
  V_STAGE(0, 0);
  V_STAGE(1, 1);
  asm volatile("s_waitcnt vmcnt(12)" ::: "memory");  // yh + K(0) done
  __builtin_amdgcn_s_barrier();
  QK_COMPUTE(0, acc2[0]);

#pragma unroll 2
  for (int jt = 0; jt < 16; jt++) {
    const int p = jt & 1;
    // entry wait: drains K(jt+1) (+ yh(jt)), leaves V(jt+1) in flight
    if (jt < 15) { asm volatile("s_waitcnt vmcnt(4)" ::: "memory"); }
    else         { asm volatile("s_waitcnt vmcnt(0)" ::: "memory"); }
    __builtin_amdgcn_s_barrier();

    if (jt < 14) K_STAGE(jt + 2, p);          // Kbuf p free (K(jt) last read in iter jt-1)
    if (jt < 15) QK_COMPUTE(jt + 1, acc2[(jt + 1) & 1]);   // overlaps SM(jt) below

    // ---- SM(jt) on acc2[p]
    f32x4* acc = acc2[p];
#pragma unroll
    for (int fn = 0; fn < 4; fn++)
#pragma unroll
      for (int r = 0; r < 4; r++)
        acc[fn][r] += xwh[fn & 1][r] + ((fn >> 1) ? yh1 : yh0);

    float mx = fmaxf(fmaxf(fmaxf(acc[0][0], acc[0][1]), fmaxf(acc[0][2], acc[0][3])),
                     fmaxf(fmaxf(acc[1][0], acc[1][1]), fmaxf(acc[1][2], acc[1][3])));
    mx = fmaxf(mx, fmaxf(fmaxf(fmaxf(acc[2][0], acc[2][1]), fmaxf(acc[2][2], acc[2][3])),
                         fmaxf(fmaxf(acc[3][0], acc[3][1]), fmaxf(acc[3][2], acc[3][3]))));
    mx = fmaxf(mx, __shfl_xor(mx, 16));
    mx = fmaxf(mx, __shfl_xor(mx, 32));

    if (__any(mx > m_q + 8.f)) {   // defer-max (exp2 domain)
      const float mnew = fmaxf(m_q, mx);
      const float scq = exp2f(m_q - mnew);
      m_q = mnew;
      l_q *= scq;
#pragma unroll
      for (int r = 0; r < 4; r++) {
        const float scr = __shfl(scq, g*4 + r, 16);
#pragma unroll
        for (int fd = 0; fd < 8; fd++) Oacc[fd][r] *= scr;
      }
    }

    float pv[4][4];
    float ps = 0.f;
#pragma unroll
    for (int fn = 0; fn < 4; fn++) {
#pragma unroll
      for (int r = 0; r < 4; r++) {
        pv[fn][r] = exp2f(acc[fn][r] - m_q);
        ps += pv[fn][r];
      }
    }
    ps += __shfl_xor(ps, 16);
    ps += __shfl_xor(ps, 32);
    l_q += ps;

    // next-tile yh prefetch (before V_STAGE so wait-counting stays exact)
    float nyh0 = 0.f, nyh1 = 0.f;
    if (jt < 15) { nyh0 = rhb[(jt + 1)*2]; nyh1 = rhb[(jt + 1)*2 + 1]; }

    // P pack -> Pl[q=c][kv]
    {
      char* pb = Pl + w*2048 + c*128;
      const int swz = (c & 7) << 4;
#pragma unroll
      for (int fn = 0; fn < 4; fn++) {
        u32 w0, w1;
        asm("v_cvt_pk_bf16_f32 %0, %1, %2" : "=v"(w0) : "v"(pv[fn][0]), "v"(pv[fn][1]));
        asm("v_cvt_pk_bf16_f32 %0, %1, %2" : "=v"(w1) : "v"(pv[fn][2]), "v"(pv[fn][3]));
        uint2 pk; pk.x = w0; pk.y = w1;
        *(uint2*)(pb + ((fn*32 + g*8) ^ swz)) = pk;
      }
    }

    // ---- PV(jt): V from Vbuf p
    __builtin_amdgcn_s_setprio(1);
    {
      const char* Vs_ = sm + 32768 + p*16384;
#pragma unroll
      for (int s = 0; s < 2; s++) {
        const int koff = (s*64 + g*16) ^ ((c & 7) << 4);
        bf16x8 pf = *(const bf16x8*)(Pl + w*2048 + c*128 + koff);
#pragma unroll
        for (int fd = 0; fd < 8; fd++) {
          bf16x8 vf = *(const bf16x8*)(Vs_ + (fd*16 + c)*128 + koff);
          Oacc[fd] = __builtin_amdgcn_mfma_f32_16x16x32_bf16(pf, vf, Oacc[fd], 0, 0, 0);
        }
      }
    }
    __builtin_amdgcn_s_setprio(0);

    __builtin_amdgcn_s_barrier();             // all waves done reading V(jt) / K(jt+1) staged regions
    if (jt < 14) V_STAGE(jt + 2, p);          // Vbuf p free now
    yh0 = nyh0; yh1 = nyh1;
  }
#undef K_STAGE
#undef V_STAGE
#undef QK_COMPUTE

  const int b = bh >> 2, h = bh & 3;
#pragma unroll
  for (int r = 0; r < 4; r++) {
    const float lr = __shfl(l_q, g*4 + r, 16);
    const float linv = 1.0f / lr;
    const int io = i0 + w*16 + g*4 + r;
#pragma unroll
    for (int fd = 0; fd < 8; fd++) {
      AO[(size_t)(b*1024 + io)*512 + h*128 + fd*16 + c] = f2b(Oacc[fd][r] * linv);
    }
  }
}

// ---------------- output GEMM (128x128 tile, 4 waves, 2-deep pipeline; R12) ----------
__global__ __launch_bounds__(256) void gemm_out(
    const u16* __restrict__ A, const u16* __restrict__ Bt, float* __restrict__ outF)
{
  __shared__ char sm[65536];
  const int tid = threadIdx.x;
  const int w = tid >> 6, l = tid & 63, g = l >> 4, c = l & 15;
  const int bm = blockIdx.x, bn = blockIdx.y;
  const int wm = (w >> 1) * 64, wn = (w & 1) * 64;

  f32x4 acc[4][4];
#pragma unroll
  for (int i = 0; i < 4; i++)
#pragma unroll
    for (int j = 0; j < 4; j++) acc[i][j] = f32x4{0.f, 0.f, 0.f, 0.f};

  const char* Ab = (const char*)A;
  const char* Bb = (const char*)Bt;
  const int rsub = l >> 3;
  const int csw = (((l & 7) ^ rsub) << 4);

#define G_STAGE(kb, p)                                                                    \
  {                                                                                       \
    char* As_ = sm + (p)*32768;                                                           \
    char* Bs_ = As_ + 16384;                                                              \
    const int kbyte = (kb) * 128;                                                         \
    _Pragma("unroll")                                                                     \
    for (int t = 0; t < 4; t++) {                                                         \
      const int row = (w*4 + t)*8 + rsub;                                                 \
      glds16(Ab + (size_t)(bm*128 + row) * 1024 + kbyte + csw, As_ + (w*4 + t)*1024);     \
      glds16(Bb + (size_t)(bn*128 + row) * 1024 + kbyte + csw, Bs_ + (w*4 + t)*1024);     \
    }                                                                                     \
  }

  G_STAGE(0, 0);
  G_STAGE(1, 1);

#pragma unroll
  for (int kb = 0; kb < 8; kb++) {
    const int p = kb & 1;
    if (kb < 7) { asm volatile("s_waitcnt vmcnt(8)" ::: "memory"); }
    else        { asm volatile("s_waitcnt vmcnt(0)" ::: "memory"); }
    __builtin_amdgcn_s_barrier();
    const char* As_ = sm + p*32768;
    const char* Bs_ = As_ + 16384;
#pragma unroll
    for (int ks = 0; ks < 2; ks++) {
      const int koff = (ks*64 + g*16) ^ ((c & 7) << 4);
      bf16x8 af[4], bfr[4];
#pragma unroll
      for (int mf = 0; mf < 4; mf++)
        af[mf] = *(const bf16x8*)(As_ + (wm + mf*16 + c)*128 + koff);
#pragma unroll
      for (int nf = 0; nf < 4; nf++)
        bfr[nf] = *(const bf16x8*)(Bs_ + (wn + nf*16 + c)*128 + koff);
#pragma unroll
      for (int mf = 0; mf < 4; mf++)
#pragma unroll
        for (int nf = 0; nf < 4; nf++)
          acc[mf][nf] = __builtin_amdgcn_mfma_f32_16x16x32_bf16(af[mf], bfr[nf], acc[mf][nf], 0, 0, 0);
    }
    __builtin_amdgcn_s_barrier();
    if (kb < 6) G_STAGE(kb + 2, p);
  }
#undef G_STAGE

#pragma unroll
  for (int mf = 0; mf < 4; mf++) {
#pragma unroll
    for (int nf = 0; nf < 4; nf++) {
      const int n = bn*128 + wn + nf*16 + c;
#pragma unroll
      for (int r = 0; r < 4; r++) {
        const int m = bm*128 + wm + mf*16 + g*4 + r;
        outF[(size_t)m*512 + n] = acc[mf][nf][r];
      }
    }
  }
}

// ---------------- launcher ----------------
extern "C" void kernel_launch(void* const* d_in, const int* in_sizes, int n_in,
                              void* d_out, int out_size, void* d_ws, size_t ws_size,
                              hipStream_t stream) {
  const float* x   = (const float*)d_in[0];
  const float* Wq  = (const float*)d_in[1];
  const float* Wk  = (const float*)d_in[2];
  const float* Wv  = (const float*)d_in[3];
  const float* Wo  = (const float*)d_in[4];
  const float* pew = (const float*)d_in[5];
  const float* peh = (const float*)d_in[6];

  char* ws = (char*)d_ws;
  u16* xb    = (u16*)ws;    ws += (size_t)8192*512*2;
  u16* WbigT = (u16*)ws;    ws += (size_t)2048*512*2;
  u16* WoT   = (u16*)ws;    ws += (size_t)512*512*2;
  u16* Qb    = (u16*)ws;    ws += (size_t)32*1024*128*2;
  u16* Kb    = (u16*)ws;    ws += (size_t)32*1024*128*2;
  u16* Vt    = (u16*)ws;    ws += (size_t)32*1024*128*2;
  float* RELW = (float*)ws; ws += (size_t)32*1024*64*4;
  float* RELH = (float*)ws; ws += (size_t)32*1024*64*4;
  u16* AO    = (u16*)ws;    ws += (size_t)8192*512*2;

  prep_all<<<6664, 256, 0, stream>>>(x, Wq, Wk, Wv, Wo, pew, peh, xb, WbigT, WoT);
  gemm256<<<dim3(32, 8), 512, 0, stream>>>(xb, WbigT, Qb, Kb, Vt, RELW, RELH);
  attn_fused<<<dim3(32, 16), 256, 0, stream>>>(Qb, Kb, Vt, RELW, RELH, AO);
  gemm_out<<<dim3(64, 4), 256, 0, stream>>>(AO, WoT, (float*)d_out);
}

// Round 14
// 97.422 us; speedup vs baseline: 1.0378x; 1.0378x over previous
//
#include <hip/hip_runtime.h>
#include <math.h>

typedef unsigned short u16;
typedef unsigned int u32;
typedef __bf16 bf16x8 __attribute__((ext_vector_type(8)));
typedef float f32x4 __attribute__((ext_vector_type(4)));

__device__ __forceinline__ u16 f2b(float f) {
  u32 u = __builtin_bit_cast(u32, f);
  u32 r = (u + 0x7FFFu + ((u >> 16) & 1u)) >> 16;
  return (u16)r;
}

__device__ __forceinline__ void glds16(const void* g, void* lds) {
  __builtin_amdgcn_global_load_lds(
      (const __attribute__((address_space(1))) void*)(void*)(const_cast<void*>(g)),
      (__attribute__((address_space(3))) void*)lds, 16, 0, 0);
}

// scale folded with log2(e) so softmax uses native exp2 (v_exp_f32); validated R11/R12
#define QSCALE (0.08838834764831845f * 1.4426950408889634f)

// ---------------- merged prep kernel (castx | buildw | wpe) ----------------
__global__ __launch_bounds__(256) void prep_all(
    const float* __restrict__ x, const float* __restrict__ Wq, const float* __restrict__ Wk,
    const float* __restrict__ Wv, const float* __restrict__ Wo,
    const float* __restrict__ pew, const float* __restrict__ peh,
    u16* __restrict__ xb, u16* __restrict__ WbigT, u16* __restrict__ WoT)
{
  __shared__ float wrow[512];
  const int bid = blockIdx.x;
  const int t = threadIdx.x;
  if (bid < 4096) {
    int idx = bid * 256 + t;
    float4 v = ((const float4*)x)[idx];
    ushort4 o;
    o.x = f2b(v.x); o.y = f2b(v.y); o.z = f2b(v.z); o.w = f2b(v.w);
    ((ushort4*)xb)[idx] = o;
  } else if (bid < 6152) {
    int row = bid - 4096;  // 0..2055
    if (row < 512) {
      for (int k = t; k < 512; k += 256) WbigT[row*512 + k] = f2b(Wq[k*512 + row] * QSCALE);
    } else if (row < 1024) {
      int n = row - 512;
      for (int k = t; k < 512; k += 256) WbigT[row*512 + k] = f2b(Wk[k*512 + n]);
    } else if (row < 1536) {
      int n = row - 1024;
      for (int k = t; k < 512; k += 256) WbigT[row*512 + k] = f2b(Wv[k*512 + n]);
    } else if (row < 1544) {
      int rr = row - 1536 + 2040;
      for (int k = t; k < 512; k += 256) WbigT[rr*512 + k] = 0;
    } else {
      int n = row - 1544;
      for (int k = t; k < 512; k += 256) WoT[n*512 + k] = f2b(Wo[k*512 + n]);
    }
  } else {
    int k = bid - 6152;  // 0..511
    for (int j = t; j < 512; j += 256) wrow[j] = Wq[k*512 + j];
    __syncthreads();
    if (t < 252) {
      int h = t / 63, r = t - h*63;
      float aw = 0.f, ah = 0.f;
      for (int d = 0; d < 128; d++) {
        float qv = wrow[h*128 + d];
        aw += qv * pew[d*63 + r];
        ah += qv * peh[d*63 + r];
      }
      WbigT[(size_t)(1536 + t)*512 + k] = f2b(aw * QSCALE);
      WbigT[(size_t)(1788 + t)*512 + k] = f2b(ah * QSCALE);
    }
  }
}

// ---------------- fused QKV+REL GEMM: 256x256 tile, 8 waves, phase-interleaved (R10/R12) ------
__global__ __launch_bounds__(512) void gemm256(
    const u16* __restrict__ A, const u16* __restrict__ Bt,
    u16* __restrict__ Qb, u16* __restrict__ Kb, u16* __restrict__ Vt,
    float* __restrict__ RELW, float* __restrict__ RELH)
{
  __shared__ char sm[131072];
  const int tid = threadIdx.x;
  const int w = tid >> 6, l = tid & 63, g = l >> 4, c = l & 15;
  const int bm = blockIdx.x, bn = blockIdx.y;
  const int wm = w >> 2, wn = w & 3;

  f32x4 acc[8][4];
#pragma unroll
  for (int i = 0; i < 8; i++)
#pragma unroll
    for (int j = 0; j < 4; j++) acc[i][j] = f32x4{0.f, 0.f, 0.f, 0.f};

  const char* Ab = (const char*)A;
  const char* Bb = (const char*)Bt;
  const int rsub = l >> 3;
  const int csw = (((l & 7) ^ rsub) << 4);

#define A_STAGE(kb, p)                                                                    \
  {                                                                                       \
    char* As_ = sm + (p)*65536;                                                           \
    const int kbyte = (kb) * 128;                                                         \
    _Pragma("unroll")                                                                     \
    for (int i2 = 0; i2 < 4; i2++) {                                                      \
      const int row = i2*64 + w*8 + rsub;                                                 \
      glds16(Ab + (size_t)(bm*256 + row) * 1024 + kbyte + csw, As_ + i2*8192 + w*1024);   \
    }                                                                                     \
  }
#define B_STAGE(kb, p)                                                                    \
  {                                                                                       \
    char* Bs_ = sm + (p)*65536 + 32768;                                                   \
    const int kbyte = (kb) * 128;                                                         \
    _Pragma("unroll")                                                                     \
    for (int i2 = 0; i2 < 4; i2++) {                                                      \
      const int row = i2*64 + w*8 + rsub;                                                 \
      glds16(Bb + (size_t)(bn*256 + row) * 1024 + kbyte + csw, Bs_ + i2*8192 + w*1024);   \
    }                                                                                     \
  }

  B_STAGE(0, 0); A_STAGE(0, 0);
  B_STAGE(1, 1); A_STAGE(1, 1);

#pragma unroll
  for (int kb = 0; kb < 8; kb++) {
    const int p = kb & 1;
    if (kb == 0)      { asm volatile("s_waitcnt vmcnt(8)" ::: "memory"); }
    else if (kb < 7)  { asm volatile("s_waitcnt vmcnt(4)" ::: "memory"); }
    else              { asm volatile("s_waitcnt vmcnt(0)" ::: "memory"); }
    __builtin_amdgcn_s_barrier();

    const char* As_ = sm + p*65536;
    const char* Bs_ = As_ + 32768;

    bf16x8 bf[4][2], af[4][2];
#pragma unroll
    for (int ks = 0; ks < 2; ks++) {
      const int koff = (ks*64 + g*16) ^ ((c & 7) << 4);
#pragma unroll
      for (int mf = 0; mf < 4; mf++)
        af[mf][ks] = *(const bf16x8*)(As_ + (wm*128 + mf*16 + c)*128 + koff);
#pragma unroll
      for (int nf = 0; nf < 4; nf++)
        bf[nf][ks] = *(const bf16x8*)(Bs_ + (wn*64 + nf*16 + c)*128 + koff);
    }
    if (kb >= 1 && kb < 7) A_STAGE(kb + 1, p ^ 1);
    __builtin_amdgcn_s_setprio(1);
#pragma unroll
    for (int ks = 0; ks < 2; ks++)
#pragma unroll
      for (int mf = 0; mf < 4; mf++)
#pragma unroll
        for (int nf = 0; nf < 4; nf++)
          acc[mf][nf] = __builtin_amdgcn_mfma_f32_16x16x32_bf16(af[mf][ks], bf[nf][ks], acc[mf][nf], 0, 0, 0);
    __builtin_amdgcn_s_setprio(0);
    __builtin_amdgcn_s_barrier();

#pragma unroll
    for (int ks = 0; ks < 2; ks++) {
      const int koff = (ks*64 + g*16) ^ ((c & 7) << 4);
#pragma unroll
      for (int mf = 0; mf < 4; mf++)
        af[mf][ks] = *(const bf16x8*)(As_ + (wm*128 + (mf + 4)*16 + c)*128 + koff);
    }
    if (kb < 6) B_STAGE(kb + 2, p);
    __builtin_amdgcn_s_setprio(1);
#pragma unroll
    for (int ks = 0; ks < 2; ks++)
#pragma unroll
      for (int mf = 0; mf < 4; mf++)
#pragma unroll
        for (int nf = 0; nf < 4; nf++)
          acc[mf + 4][nf] = __builtin_amdgcn_mfma_f32_16x16x32_bf16(af[mf][ks], bf[nf][ks], acc[mf + 4][nf], 0, 0, 0);
    __builtin_amdgcn_s_setprio(0);
    __builtin_amdgcn_s_barrier();
  }
#undef A_STAGE
#undef B_STAGE

  const int b = bm >> 2;
  const int iBase = (bm & 3) * 256;

  if (bn < 4) {
    u16* dst0 = (bn < 2) ? Qb : Kb;
    const int bnn = bn & 1;
#pragma unroll
    for (int mf = 0; mf < 8; mf++) {
      const int lmb = wm*128 + mf*16 + g*4;
#pragma unroll
      for (int nf = 0; nf < 4; nf++) {
        const int ln = wn*64 + nf*16 + c;
#pragma unroll
        for (int r = 0; r < 4; r++) {
          const int lm = lmb + r;
          *(u16*)(sm + lm*512 + ((ln*2) ^ ((lm & 7) << 4))) = f2b(acc[mf][nf][r]);
        }
      }
    }
    __builtin_amdgcn_s_barrier();
#pragma unroll
    for (int it = 0; it < 16; it++) {
      const int gid = it*512 + tid;
      const int lm2 = gid >> 5, gsub = gid & 31;
      bf16x8 v = *(const bf16x8*)(sm + lm2*512 + ((gsub*16) ^ ((lm2 & 7) << 4)));
      const int h = bnn*2 + (gsub >> 4);
      const int d0 = (gsub & 15) * 8;
      *(bf16x8*)(dst0 + ((size_t)(b*4 + h)*1024 + iBase + lm2)*128 + d0) = v;
    }
  } else if (bn < 6) {
#pragma unroll
    for (int mf = 0; mf < 8; mf++) {
      const int lmb = wm*128 + mf*16 + g*4;
#pragma unroll
      for (int nf = 0; nf < 4; nf++) {
        const int ln = wn*64 + nf*16 + c;
        u32 w0, w1;
        asm("v_cvt_pk_bf16_f32 %0, %1, %2" : "=v"(w0) : "v"(acc[mf][nf][0]), "v"(acc[mf][nf][1]));
        asm("v_cvt_pk_bf16_f32 %0, %1, %2" : "=v"(w1) : "v"(acc[mf][nf][2]), "v"(acc[mf][nf][3]));
        uint2 pk; pk.x = w0; pk.y = w1;
        *(uint2*)(sm + ln*512 + ((lmb*2) ^ ((c & 7) << 4))) = pk;
      }
    }
    __builtin_amdgcn_s_barrier();
#pragma unroll
    for (int it = 0; it < 16; it++) {
      const int gid = it*512 + tid;
      const int ln2 = gid >> 5, gsub = gid & 31;
      bf16x8 v = *(const bf16x8*)(sm + ln2*512 + ((gsub*16) ^ ((ln2 & 7) << 4)));
      const int q2 = (bn - 4)*256 + ln2;
      const int h = q2 >> 7, d = q2 & 127;
      *(bf16x8*)(Vt + ((size_t)(b*4 + h)*128 + d)*1024 + iBase + gsub*8) = v;
    }
  } else {
#pragma unroll
    for (int mf = 0; mf < 8; mf++) {
      const int lmb = wm*128 + mf*16 + g*4;
#pragma unroll
      for (int nf = 0; nf < 4; nf++) {
        const int q = (bn - 6)*256 + wn*64 + nf*16 + c;
        if (q < 252) {
          const int h = q / 63, r2 = q - h*63;
#pragma unroll
          for (int r = 0; r < 4; r++)
            RELW[(size_t)((b*4 + h)*1024 + iBase + lmb + r)*64 + r2] = acc[mf][nf][r];
        } else if (q < 504) {
          const int qq = q - 252;
          const int h = qq / 63, r2 = qq - h*63;
#pragma unroll
          for (int r = 0; r < 4; r++)
            RELH[(size_t)((b*4 + h)*1024 + iBase + lmb + r)*64 + r2] = acc[mf][nf][r];
        }
      }
    }
  }
}

// ---------------- fused flash attention, QBLK=128 (8 waves), R12 loop structure ----------------
// grid (32 bh, 8 q-tiles), 512 threads. LDS 80KB: K dbuf 2x16K @0, V dbuf 2x16K @32K, Pl 16K @64K.
// Per K/V tile staged once per 128 q-rows (was 64): staging ops, barrier events, FETCH all halve.
__global__ __launch_bounds__(512) void attn_fused(
    const u16* __restrict__ Qb, const u16* __restrict__ Kb, const u16* __restrict__ Vt,
    const float* __restrict__ RELW, const float* __restrict__ RELH,
    u16* __restrict__ AO)
{
  __shared__ char sm[81920];
  char* const Pl = sm + 65536;
  const int tid = threadIdx.x;
  const int w = tid >> 6, l = tid & 63, g = l >> 4, c = l & 15;   // w in [0,8)
  const int bh = blockIdx.x, qt = blockIdx.y;
  const int i0 = qt * 128;

  bf16x8 qf[4];
  {
    const char* qbase = (const char*)Qb + (size_t)(bh*1024 + i0 + w*16 + c) * 256;
#pragma unroll
    for (int s = 0; s < 4; s++) qf[s] = *(const bf16x8*)(qbase + s*64 + g*16);
  }

  const int i = i0 + w*16 + c;
  const int xi = i & 31, yi = i >> 5;
  const float* rw = RELW + ((size_t)(bh*1024 + i) << 6);
  const float* rhb = RELH + ((size_t)(bh*1024 + i) << 6) + (31 - yi);
  float xwh[2][4];
#pragma unroll
  for (int e = 0; e < 2; e++)
#pragma unroll
    for (int r = 0; r < 4; r++) xwh[e][r] = rw[e*16 + g*4 + r - xi + 31];

  f32x4 Oacc[8];
#pragma unroll
  for (int fd = 0; fd < 8; fd++) Oacc[fd] = f32x4{0.f, 0.f, 0.f, 0.f};
  float m_q = -INFINITY, l_q = 0.f;

  // stage one 64-kv tile (K 16KB + V 16KB), 4 glds/thread, linear dest = chunk base + lane*16
#define A_STAGE(jt, p)                                                                     \
  {                                                                                        \
    char* Kt_ = sm + (p)*16384;                                                            \
    char* Vs_ = sm + 32768 + (p)*16384;                                                    \
    const int j0b = (jt) * 64;                                                             \
    _Pragma("unroll")                                                                      \
    for (int t = 0; t < 2; t++) {                                                          \
      const int L = (w*2 + t)*1024 + l*16;                                                 \
      const int jr = L >> 8, jb = L & 255;                                                 \
      glds16((const char*)Kb + (size_t)(bh*1024 + j0b + jr) * 256 + (jb ^ ((jr & 7) << 4)),\
             Kt_ + L);                                                                     \
      const int dr = L >> 7, db = L & 127;                                                 \
      glds16((const char*)Vt + (size_t)(bh*128 + dr) * 2048 + j0b*2 + (db ^ ((dr & 7) << 4)),\
             Vs_ + L);                                                                     \
    }                                                                                      \
  }

  // prologue: yh first (oldest vmem ops), then tiles 0,1
  float yh0 = rhb[0], yh1 = rhb[1];
  asm volatile("" ::: "memory");
  A_STAGE(0, 0);
  A_STAGE(1, 1);

#pragma unroll 2
  for (int jt = 0; jt < 16; jt++) {
    const int p = jt & 1;
    // entry: drain everything except stage(jt+1)'s 4 ops
    if (jt < 15) { asm volatile("s_waitcnt vmcnt(4)" ::: "memory"); }
    else         { asm volatile("s_waitcnt vmcnt(0)" ::: "memory"); }
    __builtin_amdgcn_s_barrier();

    const char* Kt_ = sm + p*16384;
    const char* Vs_ = sm + 32768 + p*16384;

    f32x4 acc[4];
#pragma unroll
    for (int fn = 0; fn < 4; fn++) acc[fn] = f32x4{0.f, 0.f, 0.f, 0.f};
    __builtin_amdgcn_s_setprio(1);
#pragma unroll
    for (int s = 0; s < 4; s++) {
      const int koff = (s*64 + g*16) ^ ((c & 7) << 4);
#pragma unroll
      for (int fn = 0; fn < 4; fn++) {
        bf16x8 kf = *(const bf16x8*)(Kt_ + (fn*16 + c)*256 + koff);
        acc[fn] = __builtin_amdgcn_mfma_f32_16x16x32_bf16(kf, qf[s], acc[fn], 0, 0, 0);
      }
    }
    __builtin_amdgcn_s_setprio(0);

#pragma unroll
    for (int fn = 0; fn < 4; fn++)
#pragma unroll
      for (int r = 0; r < 4; r++)
        acc[fn][r] += xwh[fn & 1][r] + ((fn >> 1) ? yh1 : yh0);

    float mx = fmaxf(fmaxf(fmaxf(acc[0][0], acc[0][1]), fmaxf(acc[0][2], acc[0][3])),
                     fmaxf(fmaxf(acc[1][0], acc[1][1]), fmaxf(acc[1][2], acc[1][3])));
    mx = fmaxf(mx, fmaxf(fmaxf(fmaxf(acc[2][0], acc[2][1]), fmaxf(acc[2][2], acc[2][3])),
                         fmaxf(fmaxf(acc[3][0], acc[3][1]), fmaxf(acc[3][2], acc[3][3]))));
    mx = fmaxf(mx, __shfl_xor(mx, 16));
    mx = fmaxf(mx, __shfl_xor(mx, 32));

    if (__any(mx > m_q + 8.f)) {   // defer-max (exp2 domain, thr=8 -> P<=256)
      const float mnew = fmaxf(m_q, mx);
      const float scq = exp2f(m_q - mnew);
      m_q = mnew;
      l_q *= scq;
#pragma unroll
      for (int r = 0; r < 4; r++) {
        const float scr = __shfl(scq, g*4 + r, 16);
#pragma unroll
        for (int fd = 0; fd < 8; fd++) Oacc[fd][r] *= scr;
      }
    }

    float pv[4][4];
    float ps = 0.f;
#pragma unroll
    for (int fn = 0; fn < 4; fn++) {
#pragma unroll
      for (int r = 0; r < 4; r++) {
        pv[fn][r] = exp2f(acc[fn][r] - m_q);
        ps += pv[fn][r];
      }
    }
    ps += __shfl_xor(ps, 16);
    ps += __shfl_xor(ps, 32);
    l_q += ps;

    // next-tile yh prefetch BEFORE the next stage (keeps vmcnt counting exact)
    float nyh0 = 0.f, nyh1 = 0.f;
    if (jt < 15) { nyh0 = rhb[(jt + 1)*2]; nyh1 = rhb[(jt + 1)*2 + 1]; }

    {
      char* pb = Pl + w*2048 + c*128;
      const int swz = (c & 7) << 4;
#pragma unroll
      for (int fn = 0; fn < 4; fn++) {
        u32 w0, w1;
        asm("v_cvt_pk_bf16_f32 %0, %1, %2" : "=v"(w0) : "v"(pv[fn][0]), "v"(pv[fn][1]));
        asm("v_cvt_pk_bf16_f32 %0, %1, %2" : "=v"(w1) : "v"(pv[fn][2]), "v"(pv[fn][3]));
        uint2 pk; pk.x = w0; pk.y = w1;
        *(uint2*)(pb + ((fn*32 + g*8) ^ swz)) = pk;
      }
    }

    __builtin_amdgcn_s_setprio(1);
#pragma unroll
    for (int s = 0; s < 2; s++) {
      const int koff = (s*64 + g*16) ^ ((c & 7) << 4);
      bf16x8 pf = *(const bf16x8*)(Pl + w*2048 + c*128 + koff);
#pragma unroll
      for (int fd = 0; fd < 8; fd++) {
        bf16x8 vf = *(const bf16x8*)(Vs_ + (fd*16 + c)*128 + koff);
        Oacc[fd] = __builtin_amdgcn_mfma_f32_16x16x32_bf16(pf, vf, Oacc[fd], 0, 0, 0);
      }
    }
    __builtin_amdgcn_s_setprio(0);

    __builtin_amdgcn_s_barrier();   // all waves done reading buf p
    if (jt < 14) A_STAGE(jt + 2, p);
    yh0 = nyh0; yh1 = nyh1;
  }
#undef A_STAGE

  const int b = bh >> 2, h = bh & 3;
#pragma unroll
  for (int r = 0; r < 4; r++) {
    const float lr = __shfl(l_q, g*4 + r, 16);
    const float linv = 1.0f / lr;
    const int io = i0 + w*16 + g*4 + r;
#pragma unroll
    for (int fd = 0; fd < 8; fd++) {
      AO[(size_t)(b*1024 + io)*512 + h*128 + fd*16 + c] = f2b(Oacc[fd][r] * linv);
    }
  }
}

// ---------------- output GEMM (128x128 tile, 4 waves, 2-deep pipeline; R12) ----------
__global__ __launch_bounds__(256) void gemm_out(
    const u16* __restrict__ A, const u16* __restrict__ Bt, float* __restrict__ outF)
{
  __shared__ char sm[65536];
  const int tid = threadIdx.x;
  const int w = tid >> 6, l = tid & 63, g = l >> 4, c = l & 15;
  const int bm = blockIdx.x, bn = blockIdx.y;
  const int wm = (w >> 1) * 64, wn = (w & 1) * 64;

  f32x4 acc[4][4];
#pragma unroll
  for (int i = 0; i < 4; i++)
#pragma unroll
    for (int j = 0; j < 4; j++) acc[i][j] = f32x4{0.f, 0.f, 0.f, 0.f};

  const char* Ab = (const char*)A;
  const char* Bb = (const char*)Bt;
  const int rsub = l >> 3;
  const int csw = (((l & 7) ^ rsub) << 4);

#define G_STAGE(kb, p)                                                                    \
  {                                                                                       \
    char* As_ = sm + (p)*32768;                                                           \
    char* Bs_ = As_ + 16384;                                                              \
    const int kbyte = (kb) * 128;                                                         \
    _Pragma("unroll")                                                                     \
    for (int t = 0; t < 4; t++) {                                                         \
      const int row = (w*4 + t)*8 + rsub;                                                 \
      glds16(Ab + (size_t)(bm*128 + row) * 1024 + kbyte + csw, As_ + (w*4 + t)*1024);     \
      glds16(Bb + (size_t)(bn*128 + row) * 1024 + kbyte + csw, Bs_ + (w*4 + t)*1024);     \
    }                                                                                     \
  }

  G_STAGE(0, 0);
  G_STAGE(1, 1);

#pragma unroll
  for (int kb = 0; kb < 8; kb++) {
    const int p = kb & 1;
    if (kb < 7) { asm volatile("s_waitcnt vmcnt(8)" ::: "memory"); }
    else        { asm volatile("s_waitcnt vmcnt(0)" ::: "memory"); }
    __builtin_amdgcn_s_barrier();
    const char* As_ = sm + p*32768;
    const char* Bs_ = As_ + 16384;
#pragma unroll
    for (int ks = 0; ks < 2; ks++) {
      const int koff = (ks*64 + g*16) ^ ((c & 7) << 4);
      bf16x8 af[4], bfr[4];
#pragma unroll
      for (int mf = 0; mf < 4; mf++)
        af[mf] = *(const bf16x8*)(As_ + (wm + mf*16 + c)*128 + koff);
#pragma unroll
      for (int nf = 0; nf < 4; nf++)
        bfr[nf] = *(const bf16x8*)(Bs_ + (wn + nf*16 + c)*128 + koff);
#pragma unroll
      for (int mf = 0; mf < 4; mf++)
#pragma unroll
        for (int nf = 0; nf < 4; nf++)
          acc[mf][nf] = __builtin_amdgcn_mfma_f32_16x16x32_bf16(af[mf], bfr[nf], acc[mf][nf], 0, 0, 0);
    }
    __builtin_amdgcn_s_barrier();
    if (kb < 6) G_STAGE(kb + 2, p);
  }
#undef G_STAGE

#pragma unroll
  for (int mf = 0; mf < 4; mf++) {
#pragma unroll
    for (int nf = 0; nf < 4; nf++) {
      const int n = bn*128 + wn + nf*16 + c;
#pragma unroll
      for (int r = 0; r < 4; r++) {
        const int m = bm*128 + wm + mf*16 + g*4 + r;
        outF[(size_t)m*512 + n] = acc[mf][nf][r];
      }
    }
  }
}

// ---------------- launcher ----------------
extern "C" void kernel_launch(void* const* d_in, const int* in_sizes, int n_in,
                              void* d_out, int out_size, void* d_ws, size_t ws_size,
                              hipStream_t stream) {
  const float* x   = (const float*)d_in[0];
  const float* Wq  = (const float*)d_in[1];
  const float* Wk  = (const float*)d_in[2];
  const float* Wv  = (const float*)d_in[3];
  const float* Wo  = (const float*)d_in[4];
  const float* pew = (const float*)d_in[5];
  const float* peh = (const float*)d_in[6];

  char* ws = (char*)d_ws;
  u16* xb    = (u16*)ws;    ws += (size_t)8192*512*2;
  u16* WbigT = (u16*)ws;    ws += (size_t)2048*512*2;
  u16* WoT   = (u16*)ws;    ws += (size_t)512*512*2;
  u16* Qb    = (u16*)ws;    ws += (size_t)32*1024*128*2;
  u16* Kb    = (u16*)ws;    ws += (size_t)32*1024*128*2;
  u16* Vt    = (u16*)ws;    ws += (size_t)32*1024*128*2;
  float* RELW = (float*)ws; ws += (size_t)32*1024*64*4;
  float* RELH = (float*)ws; ws += (size_t)32*1024*64*4;
  u16* AO    = (u16*)ws;    ws += (size_t)8192*512*2;

  prep_all<<<6664, 256, 0, stream>>>(x, Wq, Wk, Wv, Wo, pew, peh, xb, WbigT, WoT);
  gemm256<<<dim3(32, 8), 512, 0, stream>>>(xb, WbigT, Qb, Kb, Vt, RELW, RELH);
  attn_fused<<<dim3(32, 8), 512, 0, stream>>>(Qb, Kb, Vt, RELW, RELH, AO);
  gemm_out<<<dim3(64, 4), 256, 0, stream>>>(AO, WoT, (float*)d_out);
}